// Round 1
// 1016.094 us; speedup vs baseline: 1.0127x; 1.0127x over previous
//
#include <hip/hip_runtime.h>

#define HID 256
#define FANOUT 10

typedef __attribute__((ext_vector_type(8))) short bf16x8;
typedef __attribute__((ext_vector_type(4))) float f32x4;

__device__ __forceinline__ unsigned short f2bf(float f) {
    unsigned int u = __float_as_uint(f);
    u += 0x7FFFu + ((u >> 16) & 1u);
    return (unsigned short)(u >> 16);
}

// BN finalize for one channel (exact replica of the old bnfin_kernel math).
__device__ __forceinline__ void bnfin1(float s, float q, float g, float be,
                                       float invT, float& sc, float& sh) {
    const float mu = s * invT;
    float var = q * invT - mu * mu;
    var = fmaxf(var, 0.f);
    const float rs = rsqrtf(var + 1e-5f);
    sc = rs * g;
    sh = be - mu * sc;
}

// ---------------------------------------------------------------------------
// All three layers' weights -> blocked bf16: Wt[L][c*8192 + n*32 + kc]
//   = bf16( W'[c*32+kc][n] ), W' = [Wl; Wr] (K = 512).
// Block 0 additionally zero-inits the 3 stat-buffer pairs (6*256 floats).
// ---------------------------------------------------------------------------
__global__ __launch_bounds__(256)
void convw_all_kernel(const float* __restrict__ Wl0, const float* __restrict__ Wr0,
                      const float* __restrict__ Wl1, const float* __restrict__ Wr1,
                      const float* __restrict__ Wl2, const float* __restrict__ Wr2,
                      unsigned short* __restrict__ Wt,
                      float* __restrict__ stats /* 6*256 floats */) {
    if (blockIdx.x == 0) {
        for (int k = threadIdx.x; k < 1536; k += 256) stats[k] = 0.f;
    }
    const int idx = blockIdx.x * 256 + threadIdx.x;     // 0 .. 393215
    const int layer = idx >> 17, r = idx & 131071;
    const float* Wl = (layer == 0) ? Wl0 : (layer == 1) ? Wl1 : Wl2;
    const float* Wr = (layer == 0) ? Wr0 : (layer == 1) ? Wr1 : Wr2;
    const int kc = r & 31, n = (r >> 5) & 255, c = r >> 13;
    const int k = c * 32 + kc;
    const float v = (k < 256) ? Wl[k * 256 + n] : Wr[(k - 256) * 256 + n];
    Wt[idx] = f2bf(v);
}

// ---------------------------------------------------------------------------
// Fused SAGE layer: block = 64 targets, 256 threads (4 waves).
// Phase 1: wave w gathers targets w*16..w*16+15 (10-nbr mean + tlid row),
//   applying PREVIOUS layer's BN affine + ReLU on the fly (apply=1; the
//   scale/shift are finalized in-block from the prev layer's ssum/ssq —
//   replaces the standalone bnfin_kernel), and writes bf16 MFMA A-fragments
//   into LDS:
//     Alds[c*2048 + i*512 + lf*8 + j],  c = K-chunk (0..15), i = wave,
//     lf = quad*16 + m0 (fragment lane), m0 = target idx within wave.
// Phase 2 (one barrier, no LDS staging for W): K-loop, B-fragments loaded
//   straight from global Wt (contiguous 16 B per lane, L2-hot), MFMA.
// Epilogue: h store (fp32, no bias: BN cancels it) + fused BN stats
//   (shfl-reduce + one atomicAdd pair per column per block).
// ---------------------------------------------------------------------------
__global__ __launch_bounds__(256)
void fused_layer_kernel(const float* __restrict__ x, const int* __restrict__ src,
                        const int* __restrict__ tlid,
                        const unsigned short* __restrict__ Wt,
                        float* __restrict__ hbuf,
                        float* __restrict__ ssum, float* __restrict__ ssq,
                        const float* __restrict__ ssumP, const float* __restrict__ ssqP,
                        const float* __restrict__ gP, const float* __restrict__ beP,
                        float invTP, int apply) {
    __shared__ unsigned short Alds[32768];   // 64 KB
    const int tid = threadIdx.x, wave = tid >> 6, lane = tid & 63;
    const size_t rb = blockIdx.x;

    // ---- phase 1: gather + mean (+ BN/ReLU of previous layer) -> LDS frags
    const float4* x4 = (const float4*)x;
    float4 sc = make_float4(1.f, 1.f, 1.f, 1.f);
    float4 sh = make_float4(0.f, 0.f, 0.f, 0.f);
    if (apply) {
        const float4 s1 = ((const float4*)ssumP)[lane];
        const float4 q1 = ((const float4*)ssqP)[lane];
        const float4 gv = ((const float4*)gP)[lane];
        const float4 bv = ((const float4*)beP)[lane];
        bnfin1(s1.x, q1.x, gv.x, bv.x, invTP, sc.x, sh.x);
        bnfin1(s1.y, q1.y, gv.y, bv.y, invTP, sc.y, sh.y);
        bnfin1(s1.z, q1.z, gv.z, bv.z, invTP, sc.z, sh.z);
        bnfin1(s1.w, q1.w, gv.w, bv.w, invTP, sc.w, sh.w);
    }
    const int cl = lane >> 3;            // K-chunk within a 256-half (0..7)
    const int quad = (lane >> 1) & 3;    // k-octet
    const int j0 = (lane & 1) * 4;       // 0 or 4 within octet

    for (int ti = 0; ti < 16; ++ti) {
        const int t = (int)rb * 64 + wave * 16 + ti;
        const int* sp = src + (size_t)t * FANOUT;
        float sx = 0.f, sy = 0.f, sz = 0.f, sw = 0.f;
#pragma unroll
        for (int j = 0; j < FANOUT; ++j) {
            float4 v = x4[(size_t)sp[j] * 64 + lane];
            if (apply) {
                v.x = fmaxf(fmaf(v.x, sc.x, sh.x), 0.f);
                v.y = fmaxf(fmaf(v.y, sc.y, sh.y), 0.f);
                v.z = fmaxf(fmaf(v.z, sc.z, sh.z), 0.f);
                v.w = fmaxf(fmaf(v.w, sc.w, sh.w), 0.f);
            }
            sx += v.x; sy += v.y; sz += v.z; sw += v.w;
        }
        float4 tv = x4[(size_t)tlid[t] * 64 + lane];
        if (apply) {
            tv.x = fmaxf(fmaf(tv.x, sc.x, sh.x), 0.f);
            tv.y = fmaxf(fmaf(tv.y, sc.y, sh.y), 0.f);
            tv.z = fmaxf(fmaf(tv.z, sc.z, sh.z), 0.f);
            tv.w = fmaxf(fmaf(tv.w, sc.w, sh.w), 0.f);
        }
        ushort4 oa, ot;
        oa.x = f2bf(sx * 0.1f); oa.y = f2bf(sy * 0.1f);
        oa.z = f2bf(sz * 0.1f); oa.w = f2bf(sw * 0.1f);
        ot.x = f2bf(tv.x); ot.y = f2bf(tv.y); ot.z = f2bf(tv.z); ot.w = f2bf(tv.w);
        const int base = wave * 512 + (quad * 16 + ti) * 8 + j0;
        *(ushort4*)&Alds[cl * 2048 + base]       = oa;   // agg half  (chunks 0..7)
        *(ushort4*)&Alds[(cl + 8) * 2048 + base] = ot;   // tlid half (chunks 8..15)
    }
    __syncthreads();

    // ---- phase 2: K-loop, barrier-free
    f32x4 acc[4][4];
#pragma unroll
    for (int a = 0; a < 4; ++a)
#pragma unroll
        for (int b = 0; b < 4; ++b) acc[a][b] = (f32x4){0.f, 0.f, 0.f, 0.f};

    const int nb = wave * 64 + (lane & 15);
    const int ko = (lane >> 4) * 8;
#pragma unroll
    for (int c = 0; c < 16; ++c) {
        bf16x8 af[4], bfr[4];
#pragma unroll
        for (int mi = 0; mi < 4; ++mi)
            af[mi] = *(const bf16x8*)&Alds[c * 2048 + mi * 512 + lane * 8];
#pragma unroll
        for (int t = 0; t < 4; ++t)
            bfr[t] = *(const bf16x8*)&Wt[(size_t)c * 8192 + (nb + t * 16) * 32 + ko];
#pragma unroll
        for (int mi = 0; mi < 4; ++mi)
#pragma unroll
            for (int t = 0; t < 4; ++t)
                acc[mi][t] = __builtin_amdgcn_mfma_f32_16x16x32_bf16(
                    af[mi], bfr[t], acc[mi][t], 0, 0, 0);
    }

    // ---- epilogue: store h + fused BN stats
    const int q = lane >> 4, m0 = lane & 15;
#pragma unroll
    for (int t = 0; t < 4; ++t) {
        const int col = wave * 64 + t * 16 + m0;
#pragma unroll
        for (int mi = 0; mi < 4; ++mi) {
            float* op = hbuf + (rb * 64 + (size_t)mi * 16 + q * 4) * 256 + col;
#pragma unroll
            for (int r = 0; r < 4; ++r)
                op[(size_t)r * 256] = acc[mi][t][r];
        }
    }

    float s[4], sq[4];
#pragma unroll
    for (int t = 0; t < 4; ++t) {
        float a = 0.f, b = 0.f;
#pragma unroll
        for (int mi = 0; mi < 4; ++mi)
#pragma unroll
            for (int r = 0; r < 4; ++r) {
                const float v = acc[mi][t][r];
                a += v; b += v * v;
            }
        s[t] = a; sq[t] = b;
    }
#pragma unroll
    for (int t = 0; t < 4; ++t) {
        s[t] += __shfl_xor(s[t], 16);  s[t] += __shfl_xor(s[t], 32);
        sq[t] += __shfl_xor(sq[t], 16); sq[t] += __shfl_xor(sq[t], 32);
    }
    if (lane < 16) {
#pragma unroll
        for (int t = 0; t < 4; ++t) {
            const int col = wave * 64 + t * 16 + m0;
            atomicAdd(&ssum[col], s[t]);
            atomicAdd(&ssq[col], sq[t]);
        }
    }
}

// ---------------------------------------------------------------------------
// out[r,n] = relu(bn(x3))[r,:] . fc_w[:,n] + fc_b[n]   (512 x 47)
// BN finalize of layer 2 replicated per block (reads ssum2/ssq2 directly).
// ---------------------------------------------------------------------------
__global__ __launch_bounds__(64)
void fc_kernel(const float* __restrict__ x,
               const float* __restrict__ ssumP, const float* __restrict__ ssqP,
               const float* __restrict__ gP, const float* __restrict__ beP,
               float invTP,
               const float* __restrict__ w, const float* __restrict__ b,
               float* __restrict__ out, int C) {
    __shared__ float row[HID];
    const int r = blockIdx.x;
    const int tid = threadIdx.x;
    const float4 s1 = ((const float4*)ssumP)[tid];
    const float4 q1 = ((const float4*)ssqP)[tid];
    const float4 gv = ((const float4*)gP)[tid];
    const float4 bv = ((const float4*)beP)[tid];
    float4 sc, sh;
    bnfin1(s1.x, q1.x, gv.x, bv.x, invTP, sc.x, sh.x);
    bnfin1(s1.y, q1.y, gv.y, bv.y, invTP, sc.y, sh.y);
    bnfin1(s1.z, q1.z, gv.z, bv.z, invTP, sc.z, sh.z);
    bnfin1(s1.w, q1.w, gv.w, bv.w, invTP, sc.w, sh.w);
    float4 v = ((const float4*)(x + (size_t)r * HID))[tid];
    v.x = fmaxf(fmaf(v.x, sc.x, sh.x), 0.f);
    v.y = fmaxf(fmaf(v.y, sc.y, sh.y), 0.f);
    v.z = fmaxf(fmaf(v.z, sc.z, sh.z), 0.f);
    v.w = fmaxf(fmaf(v.w, sc.w, sh.w), 0.f);
    ((float4*)row)[tid] = v;
    __syncthreads();
    if (tid < C) {
        float acc = b[tid];
#pragma unroll 8
        for (int k = 0; k < HID; ++k)
            acc = fmaf(row[k], w[k * C + tid], acc);
        out[(size_t)r * C + tid] = acc;
    }
}

// ---------------------------------------------------------------------------
extern "C" void kernel_launch(void* const* d_in, const int* in_sizes, int n_in,
                              void* d_out, int out_size, void* d_ws, size_t ws_size,
                              hipStream_t stream) {
    const float* x_feat = (const float*)d_in[0];
    const int T0 = in_sizes[3];   // 61952
    const int T1 = in_sizes[11];  // 5632
    const int T2 = in_sizes[19];  // 512
    const int NCLS = in_sizes[26];

    float* buf0 = (float*)d_ws;                  // h0 (pre-norm, fp32)
    float* buf1 = buf0 + (size_t)T0 * HID;
    float* buf2 = buf1 + (size_t)T1 * HID;
    float* stats = buf2 + (size_t)T2 * HID;      // 3 pairs of (ssum, ssq)
    float* ssum0 = stats;        float* ssq0 = stats + 256;
    float* ssum1 = stats + 512;  float* ssq1 = stats + 768;
    float* ssum2 = stats + 1024; float* ssq2 = stats + 1280;
    unsigned short* Wt = (unsigned short*)(stats + 1536);   // 3 * 512*256 bf16

    const float* g0  = (const float*)d_in[7];
    const float* be0 = (const float*)d_in[8];
    const float* g1  = (const float*)d_in[15];
    const float* be1 = (const float*)d_in[16];
    const float* g2  = (const float*)d_in[23];
    const float* be2 = (const float*)d_in[24];

    convw_all_kernel<<<1536, 256, 0, stream>>>(
        (const float*)d_in[4],  (const float*)d_in[5],
        (const float*)d_in[12], (const float*)d_in[13],
        (const float*)d_in[20], (const float*)d_in[21], Wt, stats);

    // layer 0: no previous BN to apply
    fused_layer_kernel<<<T0 / 64, 256, 0, stream>>>(
        x_feat, (const int*)d_in[1], (const int*)d_in[3], Wt, buf0,
        ssum0, ssq0, nullptr, nullptr, nullptr, nullptr, 0.f, 0);

    // layer 1: applies layer-0 BN (finalized in-block from ssum0/ssq0)
    fused_layer_kernel<<<T1 / 64, 256, 0, stream>>>(
        buf0, (const int*)d_in[9], (const int*)d_in[11], Wt + (size_t)131072, buf1,
        ssum1, ssq1, ssum0, ssq0, g0, be0, 1.0f / (float)T0, 1);

    // layer 2: applies layer-1 BN
    fused_layer_kernel<<<T2 / 64, 256, 0, stream>>>(
        buf1, (const int*)d_in[17], (const int*)d_in[19], Wt + (size_t)262144, buf2,
        ssum2, ssq2, ssum1, ssq1, g1, be1, 1.0f / (float)T1, 1);

    const float* fc_w = (const float*)d_in[25];
    const float* fc_b = (const float*)d_in[26];
    fc_kernel<<<T2, 64, 0, stream>>>(
        buf2, ssum2, ssq2, g2, be2, 1.0f / (float)T2,
        fc_w, fc_b, (float*)d_out, NCLS);
}